// Round 1
// baseline (430.039 us; speedup 1.0000x reference)
//
#include <hip/hip_runtime.h>
#include <hip/hip_bf16.h>

typedef __hip_bfloat16 bf16;
typedef __attribute__((ext_vector_type(8))) short bf16x8;  // 8 bf16 = 16B
typedef __attribute__((ext_vector_type(4))) float f32x4;

#define AS1 __attribute__((address_space(1)))
#define AS3 __attribute__((address_space(3)))

__device__ __forceinline__ void async16(const void* g, void* l) {
  __builtin_amdgcn_global_load_lds((const AS1 void*)g, (AS3 void*)l, 16, 0, 0);
}

__device__ __forceinline__ float fsigmoid(float x) { return 1.0f / (1.0f + __expf(-x)); }
__device__ __forceinline__ float ftanh(float x)    { return 1.0f - 2.0f / (__expf(2.0f * x) + 1.0f); }

__device__ __forceinline__ bf16x8 pack8(float4 lo, float4 hi) {
  union { bf16x8 v; unsigned int u[4]; } r;
  r.u[0] = (__float_as_uint(lo.y) & 0xFFFF0000u) | (__float_as_uint(lo.x) >> 16);
  r.u[1] = (__float_as_uint(lo.w) & 0xFFFF0000u) | (__float_as_uint(lo.z) >> 16);
  r.u[2] = (__float_as_uint(hi.y) & 0xFFFF0000u) | (__float_as_uint(hi.x) >> 16);
  r.u[3] = (__float_as_uint(hi.w) & 0xFFFF0000u) | (__float_as_uint(hi.z) >> 16);
  return r.v;
}

// ---- prep: fp32 -> bf16 into ws.
// Layout: A[8192][2048] (x | h along K), then W'[4096][2048] where
// n' = (h>>6)*256 + gate*64 + (h&63); cols 0..1023 = W_i, 1024.. = W_h.
// 24M bf16 elems total = 48 MB.
__global__ __launch_bounds__(256) void prep_bf16(
    const float* __restrict__ x, const float* __restrict__ h,
    const float* __restrict__ wfi, const float* __restrict__ wii,
    const float* __restrict__ wgi, const float* __restrict__ woi,
    const float* __restrict__ wfh, const float* __restrict__ wih,
    const float* __restrict__ wgh, const float* __restrict__ woh,
    bf16* __restrict__ dst)
{
  const int NC = 3 * 1024 * 1024;   // 24M elems / 8
  for (int ci = blockIdx.x * 256 + threadIdx.x; ci < NC; ci += gridDim.x * 256) {
    const float* src; size_t soff, doff;
    if (ci < (1 << 20)) {                       // x
      int m = ci >> 7, k = (ci & 127) << 3;
      src = x; soff = (size_t)m * 1024 + k; doff = (size_t)m * 2048 + k;
    } else if (ci < (2 << 20)) {                // h
      int c2 = ci - (1 << 20);
      int m = c2 >> 7, k = (c2 & 127) << 3;
      src = h; soff = (size_t)m * 1024 + k; doff = (size_t)m * 2048 + 1024 + k;
    } else {                                    // weights
      int we  = ci - (2 << 20);
      int mat = we >> 17;                       // 0..7: wfi wii wgi woi wfh wih wgh woh
      int wl  = we & ((1 << 17) - 1);
      int hh  = wl >> 7, k = (wl & 127) << 3;
      int g   = mat & 3;
      src = (mat == 0) ? wfi : (mat == 1) ? wii : (mat == 2) ? wgi : (mat == 3) ? woi
          : (mat == 4) ? wfh : (mat == 5) ? wih : (mat == 6) ? wgh : woh;
      soff = (size_t)hh * 1024 + k;
      doff = (size_t)8192 * 2048
           + (size_t)(((hh >> 6) << 8) + (g << 6) + (hh & 63)) * 2048
           + ((mat >> 2) << 10) + k;
    }
    float4 lo = *(const float4*)(src + soff);
    float4 hi = *(const float4*)(src + soff + 4);
    *(bf16x8*)(dst + doff) = pack8(lo, hi);
  }
}

// ---- main: 256x256 tile, BK=64, 8 waves, 4-phase/K-tile schedule with counted
// vmcnt(8) (T3+T4), both-sides LDS chunk swizzle (T2), setprio (T5), XCD swizzle (T1).
// LDS: buf b: A at b*64KB [kh][256 rows][32 k], B at +32KB same. 128KB dbuf total.
// Swizzle: row's 16B slot s holds global chunk s^(row&3); source pre-swizzled,
// ds_read applies the same XOR. Epilogue reuses LDS as Act[4][128][66] f32 (132KB).
//
// vmcnt wait at end of phase q_, per-phase statement macro.
#define VMCNT(N) do { asm volatile("s_waitcnt vmcnt(" #N ")" ::: "memory"); \
                      __builtin_amdgcn_sched_barrier(0); } while (0)

// Phase: {ds_read frags; stage one half-tile; barrier; setprio(1); 16 MFMA;
//         setprio(0); optional vmcnt; barrier; sched_barrier}
#define PH(t_, kh_, mh_, STAGE_STMT, VMW)                                     \
  {                                                                           \
    const char* Ab = smem + (((t_) & 1) << 16) + ((kh_) << 14);               \
    const char* Bb = Ab + 32768;                                              \
    if ((mh_) == 0) {                                                         \
      _Pragma("unroll") for (int n = 0; n < 4; ++n)                           \
        bfr[n] = *(const bf16x8*)(Bb + boff + (n << 10));                     \
    }                                                                         \
    bf16x8 afr[4];                                                            \
    _Pragma("unroll") for (int i = 0; i < 4; ++i)                             \
      afr[i] = *(const bf16x8*)(Ab + aoff + ((((mh_) << 2) + i) << 10));      \
    STAGE_STMT;                                                               \
    __builtin_amdgcn_s_barrier();                                             \
    __builtin_amdgcn_s_setprio(1);                                            \
    _Pragma("unroll") for (int i = 0; i < 4; ++i)                             \
      _Pragma("unroll") for (int n = 0; n < 4; ++n)                           \
        acc[((mh_) << 2) + i][n] = __builtin_amdgcn_mfma_f32_16x16x32_bf16(   \
            afr[i], bfr[n], acc[((mh_) << 2) + i][n], 0, 0, 0);               \
    __builtin_amdgcn_s_setprio(0);                                            \
    VMW;                                                                      \
    __builtin_amdgcn_s_barrier();                                             \
    __builtin_amdgcn_sched_barrier(0);                                        \
  }

__global__ __launch_bounds__(512, 2) void lstm_mfma(
    const bf16* __restrict__ ws,
    const float* __restrict__ c,
    const float* __restrict__ bfi, const float* __restrict__ bfh,
    const float* __restrict__ bii, const float* __restrict__ bih,
    const float* __restrict__ bgi, const float* __restrict__ bgh,
    const float* __restrict__ boi, const float* __restrict__ boh,
    float* __restrict__ out)
{
  __shared__ __align__(16) char smem[135168];   // main 128KB dbuf; epi 132KB Act

  const int tid  = threadIdx.x;
  const int lane = tid & 63;
  const int w    = tid >> 6;      // wave 0..7
  const int wr   = w >> 2;        // M half (0..1)
  const int wc   = w & 3;         // N quarter == gate (0..3)
  const int l15  = lane & 15;
  const int quad = lane >> 4;

  // T1: XCD-aware bijective swizzle (512 % 8 == 0); m-fastest within XCD so the
  // 32 concurrent blocks per XCD share one B panel (L2-resident).
  const int orig = blockIdx.x;
  const int wg   = ((orig & 7) << 6) + (orig >> 3);
  const int by   = wg & 31;       // M block (32)
  const int bx   = wg >> 5;       // N block (16)
  const int bg0  = by << 8;

  const bf16* Ag = ws + (size_t)bg0 * 2048;
  const bf16* Bg = ws + (size_t)8192 * 2048 + (size_t)(bx << 8) * 2048;

  // staging per-lane constants: wave covers 16 rows/issue; lane -> (row, slot)
  const int r2 = lane >> 2;                  // row within 16
  const int sl = lane & 3;                   // dest slot
  const int schunk = ((sl ^ (r2 & 3)) << 3); // pre-swizzled SOURCE chunk (elems)

  // frag-read constants: slot = quad ^ (row&3), row&3 == l15&3
  const int slotA = ((quad ^ (l15 & 3)) << 4);
  const int aoff  = ((wr << 7) + l15) * 64 + slotA;   // + m*1024
  const int boff  = ((wc << 6) + l15) * 64 + slotA;   // + n*1024

  f32x4 acc[8][4];
#pragma unroll
  for (int i = 0; i < 8; ++i)
#pragma unroll
    for (int j = 0; j < 4; ++j) acc[i][j] = (f32x4){0.f, 0.f, 0.f, 0.f};

  auto stageA = [&](int t_, int kh_) {
    const bf16* s = Ag + (size_t)(t_ << 6) + (kh_ << 5) + schunk;
    char* d = smem + ((t_ & 1) << 16) + (kh_ << 14) + (w << 10);
#pragma unroll
    for (int r = 0; r < 2; ++r)
      async16(s + ((size_t)((((r << 3) + w) << 4) + r2)) * 2048, d + (r << 13));
  };
  auto stageB = [&](int t_, int kh_) {
    const bf16* s = Bg + (size_t)(t_ << 6) + (kh_ << 5) + schunk;
    char* d = smem + ((t_ & 1) << 16) + 32768 + (kh_ << 14) + (w << 10);
#pragma unroll
    for (int r = 0; r < 2; ++r)
      async16(s + ((size_t)((((r << 3) + w) << 4) + r2)) * 2048, d + (r << 13));
  };

  // Prologue: issue stream [Ak0(0) Bk0(0) Ak1(0) Bk1(0) Ak0(1) Bk0(1)] (12 loads),
  // then vmcnt(8) -> tile0 kh0 landed, 4 half-tiles stay in flight.
  stageA(0, 0); stageB(0, 0); stageA(0, 1); stageB(0, 1); stageA(1, 0); stageB(1, 0);
  VMCNT(8);
  __builtin_amdgcn_s_barrier();
  __builtin_amdgcn_sched_barrier(0);

  // Steady state, tiles 0..29. Issue map: q0->Ak1(t+1), q1->Bk1(t+1),
  // q2->Ak0(t+2), q3->Bk0(t+2). vmcnt(8) at each kh switch (ends of q1,q3):
  // exactly lands the 2 half-tiles the next 2 phases read; never drains to 0.
  // Overwrite safety: every slot's new write is >=1 phase-end barrier after its
  // previous readers' last ds_read (kh0 slots read q0/q1, rewritten q2/q3; kh1
  // slots of other-buf rewritten q0/q1 after prior tile's q2/q3 reads).
  for (int t = 0; t < 30; ++t) {
    bf16x8 bfr[4];
    PH(t, 0, 0, { stageA(t + 1, 1); }, )
    PH(t, 0, 1, { stageB(t + 1, 1); }, VMCNT(8))
    PH(t, 1, 0, { stageA(t + 2, 0); }, )
    PH(t, 1, 1, { stageB(t + 2, 0); }, VMCNT(8))
  }
  {  // t = 30: no t+2 stages; q3 wait shrinks to the 4 loads issued after Bk0(31)
    const int t = 30;
    bf16x8 bfr[4];
    PH(t, 0, 0, { stageA(31, 1); }, )
    PH(t, 0, 1, { stageB(31, 1); }, VMCNT(8))
    PH(t, 1, 0, , )
    PH(t, 1, 1, , VMCNT(4))
  }
  {  // t = 31: nothing issued after its kh1 halves -> drain (tail only)
    const int t = 31;
    bf16x8 bfr[4];
    PH(t, 0, 0, , )
    PH(t, 0, 1, , VMCNT(0))
    PH(t, 1, 0, , )
    PH(t, 1, 1, , )
  }

  // ---- fused LSTM epilogue: two row-half passes through Act[4][128][66] f32.
  float* Act = (float*)smem;
  const float* bI = (wc == 0) ? bfi : (wc == 1) ? bii : (wc == 2) ? bgi : boi;
  const float* bH = (wc == 0) ? bfh : (wc == 1) ? bih : (wc == 2) ? bgh : boh;
  const int hcol0 = bx << 6;
  float biasv[4];
#pragma unroll
  for (int n = 0; n < 4; ++n)
    biasv[n] = bI[hcol0 + n * 16 + l15] + bH[hcol0 + n * 16 + l15];

  const size_t outCT = (size_t)8192 * 1024;
  const bool istanh = (wc == 2);

#pragma unroll
  for (int p = 0; p < 2; ++p) {
    __syncthreads();
    if (wr == p) {
      float* Aw = Act + wc * 8448;   // [128][66], +66 pad: writes/reads 2-way
#pragma unroll
      for (int m = 0; m < 8; ++m)
#pragma unroll
        for (int n = 0; n < 4; ++n)
#pragma unroll
          for (int r = 0; r < 4; ++r) {
            const float v = acc[m][n][r] + biasv[n];
            Aw[(m * 16 + quad * 4 + r) * 66 + n * 16 + l15] = istanh ? ftanh(v) : fsigmoid(v);
          }
    }
    __syncthreads();
#pragma unroll
    for (int it = 0; it < 16; ++it) {
      const int idx = it * 512 + tid;
      const int row = idx >> 6, col = idx & 63;
      const float fv = Act[row * 66 + col];
      const float iv = Act[8448 + row * 66 + col];
      const float gv = Act[16896 + row * 66 + col];
      const float ov = Act[25344 + row * 66 + col];
      const size_t gi = (size_t)(bg0 + p * 128 + row) * 1024 + hcol0 + col;
      const float ctv = fv * c[gi] + iv * gv;
      const float htv = ov * ftanh(ctv);
      out[gi]         = htv;
      out[outCT + gi] = ctv;
    }
  }
}

// ---- fallback (register staging, original layout) if ws too small ----
__global__ __launch_bounds__(256) void lstm_fused(
    const float* __restrict__ x, const float* __restrict__ h, const float* __restrict__ c,
    const float* __restrict__ wfi, const float* __restrict__ bfi, const float* __restrict__ wfh, const float* __restrict__ bfh,
    const float* __restrict__ wii, const float* __restrict__ bii, const float* __restrict__ wih, const float* __restrict__ bih,
    const float* __restrict__ wgi, const float* __restrict__ bgi, const float* __restrict__ wgh, const float* __restrict__ bgh,
    const float* __restrict__ woi, const float* __restrict__ boi, const float* __restrict__ woh, const float* __restrict__ boh,
    float* __restrict__ out)
{
  __shared__ __align__(16) char smem[33792];
  short* As = (short*)smem;
  short* Bs = As + 8192;
  float* Epi = (float*)smem;

  const int tid  = threadIdx.x;
  const int lane = tid & 63;
  const int w    = tid >> 6;
  const int l15  = lane & 15;
  const int quad = lane >> 4;
  const int rq   = w >> 1;
  const int cq   = w & 1;
  const int rowoff = lane >> 3;
  const int ch   = lane & 7;
  const int dstch = ch ^ rowoff;

  const int bg0 = blockIdx.y << 7;
  const int hb  = blockIdx.x << 5;

  const float* WgI = (w == 0) ? wfi : (w == 1) ? wii : (w == 2) ? wgi : woi;
  const float* WgH = (w == 0) ? wfh : (w == 1) ? wih : (w == 2) ? wgh : woh;

  size_t aoff[4], boff2[4];
#pragma unroll
  for (int q = 0; q < 4; ++q) {
    const int u = (w << 2) + q;
    aoff[q]  = (size_t)((u << 3) + rowoff) * 1024 + (ch << 3);
    boff2[q] = (size_t)((q << 3) + rowoff) * 1024 + (ch << 3);
  }

  f32x4 acc[4][4];
#pragma unroll
  for (int i = 0; i < 4; ++i)
#pragma unroll
    for (int j = 0; j < 4; ++j) acc[i][j] = (f32x4){0.f, 0.f, 0.f, 0.f};

  const int arow = (rq * 64 + l15) * 64;
  const int brow = (cq * 64 + l15) * 64;
  const int sw   = l15 & 7;
  const int c0   = ((0 + quad) ^ sw) << 3;
  const int c1   = ((4 + quad) ^ sw) << 3;

  float4 A0[4], A1[4], B0[4], B1[4];
  auto issue = [&](int KT) {
    const float* Ab = ((KT < 16) ? x : h)     + (size_t)bg0 * 1024 + ((KT & 15) << 6);
    const float* Bb = ((KT < 16) ? WgI : WgH) + (size_t)hb  * 1024 + ((KT & 15) << 6);
#pragma unroll
    for (int q = 0; q < 4; ++q) {
      const float* pa = Ab + aoff[q];
      const float* pb = Bb + boff2[q];
      A0[q] = *(const float4*)pa; A1[q] = *(const float4*)(pa + 4);
      B0[q] = *(const float4*)pb; B1[q] = *(const float4*)(pb + 4);
    }
  };

  issue(0);
  for (int kt = 0; kt < 32; ++kt) {
    __syncthreads();
#pragma unroll
    for (int q = 0; q < 4; ++q) {
      const int u = (w << 2) + q;
      *(bf16x8*)(As + (u * 8 + rowoff) * 64 + (dstch << 3)) = pack8(A0[q], A1[q]);
      *(bf16x8*)(Bs + (u * 8 + rowoff) * 64 + (dstch << 3)) = pack8(B0[q], B1[q]);
    }
    __syncthreads();
    if (kt < 31) issue(kt + 1);

#pragma unroll
    for (int s = 0; s < 2; ++s) {
      const int cs = s ? c1 : c0;
      bf16x8 a[4], b[4];
#pragma unroll
      for (int i = 0; i < 4; ++i) a[i] = *(const bf16x8*)(As + arow + i * 1024 + cs);
#pragma unroll
      for (int j = 0; j < 4; ++j) b[j] = *(const bf16x8*)(Bs + brow + j * 1024 + cs);
#pragma unroll
      for (int i = 0; i < 4; ++i)
#pragma unroll
        for (int j = 0; j < 4; ++j)
          acc[i][j] = __builtin_amdgcn_mfma_f32_16x16x32_bf16(a[i], b[j], acc[i][j], 0, 0, 0);
    }
  }

  const float* bAi = cq ? bgi : bfi;
  const float* bAh = cq ? bgh : bfh;
  const float* bBi = cq ? boi : bii;
  const float* bBh = cq ? boh : bih;
  float biasv[4];
  biasv[0] = bAi[hb + l15]      + bAh[hb + l15];
  biasv[1] = bAi[hb + 16 + l15] + bAh[hb + 16 + l15];
  biasv[2] = bBi[hb + l15]      + bBh[hb + l15];
  biasv[3] = bBi[hb + 16 + l15] + bBh[hb + 16 + l15];

  const size_t outCT = (size_t)8192 * 1024;

#pragma unroll
  for (int p = 0; p < 2; ++p) {
    __syncthreads();
    if (rq == p) {
#pragma unroll
      for (int j = 0; j < 4; ++j) {
        const int  n  = cq * 64 + j * 16 + l15;
        const bool ut = (cq == 1) && (j < 2);
        const float bj = biasv[j];
#pragma unroll
        for (int i = 0; i < 4; ++i)
#pragma unroll
          for (int r = 0; r < 4; ++r) {
            const float v = acc[i][j][r] + bj;
            Epi[(i * 16 + quad * 4 + r) * 132 + n] = ut ? ftanh(v) : fsigmoid(v);
          }
      }
    }
    __syncthreads();
#pragma unroll
    for (int it = 0; it < 8; ++it) {
      const int pair = it * 256 + tid;
      const int row  = pair >> 5;
      const int hl   = pair & 31;
      const float fv = Epi[row * 132 + hl];
      const float iv = Epi[row * 132 + 32 + hl];
      const float gv = Epi[row * 132 + 64 + hl];
      const float ov = Epi[row * 132 + 96 + hl];
      const size_t idx = (size_t)(bg0 + p * 64 + row) * 1024 + hb + hl;
      const float ctv = fv * c[idx] + iv * gv;
      const float htv = ov * ftanh(ctv);
      out[idx]         = htv;
      out[outCT + idx] = ctv;
    }
  }
}

extern "C" void kernel_launch(void* const* d_in, const int* in_sizes, int n_in,
                              void* d_out, int out_size, void* d_ws, size_t ws_size,
                              hipStream_t stream) {
  const float* p[19];
  for (int i = 0; i < 19; ++i) p[i] = (const float*)d_in[i];
  const size_t need = (size_t)24 * 1024 * 1024 * sizeof(bf16);   // 48 MB
  if (ws_size >= need) {
    prep_bf16<<<dim3(2048), dim3(256), 0, stream>>>(
        p[0], p[1],
        p[3], p[7], p[11], p[15],     // wfi wii wgi woi
        p[5], p[9], p[13], p[17],     // wfh wih wgh woh
        (bf16*)d_ws);
    lstm_mfma<<<dim3(512), dim3(512), 0, stream>>>(
        (const bf16*)d_ws, p[2],
        p[4], p[6], p[8], p[10], p[12], p[14], p[16], p[18],
        (float*)d_out);
  } else {
    lstm_fused<<<dim3(32, 64), dim3(256), 0, stream>>>(
        p[0], p[1], p[2],
        p[3], p[4], p[5], p[6],
        p[7], p[8], p[9], p[10],
        p[11], p[12], p[13], p[14],
        p[15], p[16], p[17], p[18],
        (float*)d_out);
  }
}

// Round 3
// 349.914 us; speedup vs baseline: 1.2290x; 1.2290x over previous
//
#include <hip/hip_runtime.h>
#include <hip/hip_bf16.h>

typedef __hip_bfloat16 bf16;
typedef __attribute__((ext_vector_type(8))) short bf16x8;  // 8 bf16 = 16B
typedef __attribute__((ext_vector_type(4))) float f32x4;

#define AS1 __attribute__((address_space(1)))
#define AS3 __attribute__((address_space(3)))

__device__ __forceinline__ void async16(const void* g, void* l) {
  __builtin_amdgcn_global_load_lds((const AS1 void*)g, (AS3 void*)l, 16, 0, 0);
}

__device__ __forceinline__ float fsigmoid(float x) { return 1.0f / (1.0f + __expf(-x)); }
__device__ __forceinline__ float ftanh(float x)    { return 1.0f - 2.0f / (__expf(2.0f * x) + 1.0f); }

__device__ __forceinline__ bf16x8 pack8(float4 lo, float4 hi) {
  union { bf16x8 v; unsigned int u[4]; } r;
  r.u[0] = (__float_as_uint(lo.y) & 0xFFFF0000u) | (__float_as_uint(lo.x) >> 16);
  r.u[1] = (__float_as_uint(lo.w) & 0xFFFF0000u) | (__float_as_uint(lo.z) >> 16);
  r.u[2] = (__float_as_uint(hi.y) & 0xFFFF0000u) | (__float_as_uint(hi.x) >> 16);
  r.u[3] = (__float_as_uint(hi.w) & 0xFFFF0000u) | (__float_as_uint(hi.z) >> 16);
  return r.v;
}

// ---- prep: fp32 -> bf16 into ws.
// Layout: A[8192][2048] (x | h along K), then W'[4096][2048] where
// n' = (h>>6)*256 + gate*64 + (h&63); cols 0..1023 = W_i, 1024.. = W_h.
__global__ __launch_bounds__(256) void prep_bf16(
    const float* __restrict__ x, const float* __restrict__ h,
    const float* __restrict__ wfi, const float* __restrict__ wii,
    const float* __restrict__ wgi, const float* __restrict__ woi,
    const float* __restrict__ wfh, const float* __restrict__ wih,
    const float* __restrict__ wgh, const float* __restrict__ woh,
    bf16* __restrict__ dst)
{
  const int NC = 3 * 1024 * 1024;
  for (int ci = blockIdx.x * 256 + threadIdx.x; ci < NC; ci += gridDim.x * 256) {
    const float* src; size_t soff, doff;
    if (ci < (1 << 20)) {                       // x
      int m = ci >> 7, k = (ci & 127) << 3;
      src = x; soff = (size_t)m * 1024 + k; doff = (size_t)m * 2048 + k;
    } else if (ci < (2 << 20)) {                // h
      int c2 = ci - (1 << 20);
      int m = c2 >> 7, k = (c2 & 127) << 3;
      src = h; soff = (size_t)m * 1024 + k; doff = (size_t)m * 2048 + 1024 + k;
    } else {                                    // weights
      int we  = ci - (2 << 20);
      int mat = we >> 17;
      int wl  = we & ((1 << 17) - 1);
      int hh  = wl >> 7, k = (wl & 127) << 3;
      int g   = mat & 3;
      src = (mat == 0) ? wfi : (mat == 1) ? wii : (mat == 2) ? wgi : (mat == 3) ? woi
          : (mat == 4) ? wfh : (mat == 5) ? wih : (mat == 6) ? wgh : woh;
      soff = (size_t)hh * 1024 + k;
      doff = (size_t)8192 * 2048
           + (size_t)(((hh >> 6) << 8) + (g << 6) + (hh & 63)) * 2048
           + ((mat >> 2) << 10) + k;
    }
    float4 lo = *(const float4*)(src + soff);
    float4 hi = *(const float4*)(src + soff + 4);
    *(bf16x8*)(dst + doff) = pack8(lo, hi);
  }
}

// ---- main: 256x256 tile, BK=64, 8 waves, 4-phase/K-tile, counted vmcnt(8).
// LDS rows are 64B (16 banks), so row*16 mod 32 has period 2: the conflict-free
// slot swizzle is slot = quad ^ ((row>>1)&3)  [bank-quad = 4*(row&1)+slot mod 8
// then covers all 8 quads exactly twice per quarter-wave => 2-way, free].
// Round-1 used row&3 (period 4) -> 4-way conflict, 1.36e7 conflict cycles.
#define VMCNT(N) do { asm volatile("s_waitcnt vmcnt(" #N ")" ::: "memory"); \
                      __builtin_amdgcn_sched_barrier(0); } while (0)

#define PH(t_, kh_, mh_, STAGE_STMT, VMW)                                     \
  {                                                                           \
    const char* Ab = smem + (((t_) & 1) << 16) + ((kh_) << 14);               \
    const char* Bb = Ab + 32768;                                              \
    if ((mh_) == 0) {                                                         \
      _Pragma("unroll") for (int n = 0; n < 4; ++n)                           \
        bfr[n] = *(const bf16x8*)(Bb + boff + (n << 10));                     \
    }                                                                         \
    bf16x8 afr[4];                                                            \
    _Pragma("unroll") for (int i = 0; i < 4; ++i)                             \
      afr[i] = *(const bf16x8*)(Ab + aoff + ((((mh_) << 2) + i) << 10));      \
    STAGE_STMT;                                                               \
    __builtin_amdgcn_s_barrier();                                             \
    __builtin_amdgcn_s_setprio(1);                                            \
    _Pragma("unroll") for (int i = 0; i < 4; ++i)                             \
      _Pragma("unroll") for (int n = 0; n < 4; ++n)                           \
        acc[((mh_) << 2) + i][n] = __builtin_amdgcn_mfma_f32_16x16x32_bf16(   \
            afr[i], bfr[n], acc[((mh_) << 2) + i][n], 0, 0, 0);               \
    __builtin_amdgcn_s_setprio(0);                                            \
    VMW;                                                                      \
    __builtin_amdgcn_s_barrier();                                             \
  }

__global__ __launch_bounds__(512, 2) void lstm_mfma(
    const bf16* __restrict__ ws,
    const float* __restrict__ c,
    const float* __restrict__ bfi, const float* __restrict__ bfh,
    const float* __restrict__ bii, const float* __restrict__ bih,
    const float* __restrict__ bgi, const float* __restrict__ bgh,
    const float* __restrict__ boi, const float* __restrict__ boh,
    float* __restrict__ out)
{
  __shared__ __align__(16) char smem[135168];

  const int tid  = threadIdx.x;
  const int lane = tid & 63;
  const int w    = tid >> 6;
  const int wr   = w >> 2;        // M half
  const int wc   = w & 3;         // N quarter == gate
  const int l15  = lane & 15;
  const int quad = lane >> 4;

  // T1: 2D-chunked XCD map. Grid 512 = 8 XCD x 64. Each XCD owns an 8x8 block
  // region (8 A-panels + 8 B-panels = 16MB) instead of all of A.
  const int orig = blockIdx.x;
  const int xcd  = orig & 7;
  const int li   = orig >> 3;                 // 0..63
  const int by   = ((xcd >> 1) << 3) + (li & 7);   // 0..31
  const int bx   = ((xcd & 1) << 3) + (li >> 3);   // 0..15
  const int bg0  = by << 8;

  const bf16* Ag = ws + (size_t)bg0 * 2048;
  const bf16* Bg = ws + (size_t)8192 * 2048 + (size_t)(bx << 8) * 2048;

  // staging: lane -> (row r2 = lane>>2, dest slot sl = lane&3); LDS slot s at
  // row r holds global chunk s ^ ((r>>1)&3); source pre-swizzled accordingly.
  const int r2 = lane >> 2;
  const int sl = lane & 3;
  const int schunk = ((sl ^ ((r2 >> 1) & 3)) << 3);   // elems

  // frag reads: slot = quad ^ ((row>>1)&3), row == l15 mod 16
  const int slotA = ((quad ^ ((l15 >> 1) & 3)) << 4); // bytes
  const int aoff  = ((wr << 7) + l15) * 64 + slotA;
  const int boff  = ((wc << 6) + l15) * 64 + slotA;

  f32x4 acc[8][4];
#pragma unroll
  for (int i = 0; i < 8; ++i)
#pragma unroll
    for (int j = 0; j < 4; ++j) acc[i][j] = (f32x4){0.f, 0.f, 0.f, 0.f};

  auto stageA = [&](int t_, int kh_) {
    const bf16* s = Ag + (size_t)(t_ << 6) + (kh_ << 5) + schunk;
    char* d = smem + ((t_ & 1) << 16) + (kh_ << 14) + (w << 10);
#pragma unroll
    for (int r = 0; r < 2; ++r)
      async16(s + ((size_t)((((r << 3) + w) << 4) + r2)) * 2048, d + (r << 13));
  };
  auto stageB = [&](int t_, int kh_) {
    const bf16* s = Bg + (size_t)(t_ << 6) + (kh_ << 5) + schunk;
    char* d = smem + ((t_ & 1) << 16) + 32768 + (kh_ << 14) + (w << 10);
#pragma unroll
    for (int r = 0; r < 2; ++r)
      async16(s + ((size_t)((((r << 3) + w) << 4) + r2)) * 2048, d + (r << 13));
  };

  // Prologue: 12 loads; vmcnt(8) -> tile0 kh0 landed; invariant: outstanding =
  // [A(t,1), B(t,1), A(t+1,0), B(t+1,0)] entering each tile.
  stageA(0, 0); stageB(0, 0); stageA(0, 1); stageB(0, 1); stageA(1, 0); stageB(1, 0);
  VMCNT(8);
  __builtin_amdgcn_s_barrier();

  // Steady: q0->A(t+1,1), q1->B(t+1,1)+VMCNT(8) [drains A/B(t,1) for q2/q3],
  // q2->A(t+2,0), q3->B(t+2,0)+VMCNT(8) [drains A/B(t+1,0) for next q0/q1].
  for (int t = 0; t < 30; ++t) {
    bf16x8 bfr[4];
    PH(t, 0, 0, { stageA(t + 1, 1); }, )
    PH(t, 0, 1, { stageB(t + 1, 1); }, VMCNT(8))
    PH(t, 1, 0, { stageA(t + 2, 0); }, )
    PH(t, 1, 1, { stageB(t + 2, 0); }, VMCNT(8))
  }
  {  // t = 30
    const int t = 30;
    bf16x8 bfr[4];
    PH(t, 0, 0, { stageA(31, 1); }, )
    PH(t, 0, 1, { stageB(31, 1); }, VMCNT(8))
    PH(t, 1, 0, , )
    PH(t, 1, 1, , VMCNT(4))
  }
  {  // t = 31
    const int t = 31;
    bf16x8 bfr[4];
    PH(t, 0, 0, , )
    PH(t, 0, 1, , VMCNT(0))
    PH(t, 1, 0, , )
    PH(t, 1, 1, , )
  }

  // ---- fused LSTM epilogue: two row-half passes through Act[4][128][66] f32.
  float* Act = (float*)smem;
  const float* bI = (wc == 0) ? bfi : (wc == 1) ? bii : (wc == 2) ? bgi : boi;
  const float* bH = (wc == 0) ? bfh : (wc == 1) ? bih : (wc == 2) ? bgh : boh;
  const int hcol0 = bx << 6;
  float biasv[4];
#pragma unroll
  for (int n = 0; n < 4; ++n)
    biasv[n] = bI[hcol0 + n * 16 + l15] + bH[hcol0 + n * 16 + l15];

  const size_t outCT = (size_t)8192 * 1024;
  const bool istanh = (wc == 2);

#pragma unroll
  for (int p = 0; p < 2; ++p) {
    __syncthreads();
    if (wr == p) {
      float* Aw = Act + wc * 8448;   // [128][66]
#pragma unroll
      for (int m = 0; m < 8; ++m)
#pragma unroll
        for (int n = 0; n < 4; ++n)
#pragma unroll
          for (int r = 0; r < 4; ++r) {
            const float v = acc[m][n][r] + biasv[n];
            Aw[(m * 16 + quad * 4 + r) * 66 + n * 16 + l15] = istanh ? ftanh(v) : fsigmoid(v);
          }
    }
    __syncthreads();
#pragma unroll
    for (int it = 0; it < 16; ++it) {
      const int idx = it * 512 + tid;
      const int row = idx >> 6, col = idx & 63;
      const float fv = Act[row * 66 + col];
      const float iv = Act[8448 + row * 66 + col];
      const float gv = Act[16896 + row * 66 + col];
      const float ov = Act[25344 + row * 66 + col];
      const size_t gi = (size_t)(bg0 + p * 128 + row) * 1024 + hcol0 + col;
      const float ctv = fv * c[gi] + iv * gv;
      const float htv = ov * ftanh(ctv);
      out[gi]         = htv;
      out[outCT + gi] = ctv;
    }
  }
}

// ---- fallback (register staging, original layout) if ws too small ----
__global__ __launch_bounds__(256) void lstm_fused(
    const float* __restrict__ x, const float* __restrict__ h, const float* __restrict__ c,
    const float* __restrict__ wfi, const float* __restrict__ bfi, const float* __restrict__ wfh, const float* __restrict__ bfh,
    const float* __restrict__ wii, const float* __restrict__ bii, const float* __restrict__ wih, const float* __restrict__ bih,
    const float* __restrict__ wgi, const float* __restrict__ bgi, const float* __restrict__ wgh, const float* __restrict__ bgh,
    const float* __restrict__ woi, const float* __restrict__ boi, const float* __restrict__ woh, const float* __restrict__ boh,
    float* __restrict__ out)
{
  __shared__ __align__(16) char smem[33792];
  short* As = (short*)smem;
  short* Bs = As + 8192;
  float* Epi = (float*)smem;

  const int tid  = threadIdx.x;
  const int lane = tid & 63;
  const int w    = tid >> 6;
  const int l15  = lane & 15;
  const int quad = lane >> 4;
  const int rq   = w >> 1;
  const int cq   = w & 1;
  const int rowoff = lane >> 3;
  const int ch   = lane & 7;
  const int dstch = ch ^ rowoff;

  const int bg0 = blockIdx.y << 7;
  const int hb  = blockIdx.x << 5;

  const float* WgI = (w == 0) ? wfi : (w == 1) ? wii : (w == 2) ? wgi : woi;
  const float* WgH = (w == 0) ? wfh : (w == 1) ? wih : (w == 2) ? wgh : woh;

  size_t aoff[4], boff2[4];
#pragma unroll
  for (int q = 0; q < 4; ++q) {
    const int u = (w << 2) + q;
    aoff[q]  = (size_t)((u << 3) + rowoff) * 1024 + (ch << 3);
    boff2[q] = (size_t)((q << 3) + rowoff) * 1024 + (ch << 3);
  }

  f32x4 acc[4][4];
#pragma unroll
  for (int i = 0; i < 4; ++i)
#pragma unroll
    for (int j = 0; j < 4; ++j) acc[i][j] = (f32x4){0.f, 0.f, 0.f, 0.f};

  const int arow = (rq * 64 + l15) * 64;
  const int brow = (cq * 64 + l15) * 64;
  const int sw   = l15 & 7;
  const int c0   = ((0 + quad) ^ sw) << 3;
  const int c1   = ((4 + quad) ^ sw) << 3;

  float4 A0[4], A1[4], B0[4], B1[4];
  auto issue = [&](int KT) {
    const float* Ab = ((KT < 16) ? x : h)     + (size_t)bg0 * 1024 + ((KT & 15) << 6);
    const float* Bb = ((KT < 16) ? WgI : WgH) + (size_t)hb  * 1024 + ((KT & 15) << 6);
#pragma unroll
    for (int q = 0; q < 4; ++q) {
      const float* pa = Ab + aoff[q];
      const float* pb = Bb + boff2[q];
      A0[q] = *(const float4*)pa; A1[q] = *(const float4*)(pa + 4);
      B0[q] = *(const float4*)pb; B1[q] = *(const float4*)(pb + 4);
    }
  };

  issue(0);
  for (int kt = 0; kt < 32; ++kt) {
    __syncthreads();
#pragma unroll
    for (int q = 0; q < 4; ++q) {
      const int u = (w << 2) + q;
      *(bf16x8*)(As + (u * 8 + rowoff) * 64 + (dstch << 3)) = pack8(A0[q], A1[q]);
      *(bf16x8*)(Bs + (u * 8 + rowoff) * 64 + (dstch << 3)) = pack8(B0[q], B1[q]);
    }
    __syncthreads();
    if (kt < 31) issue(kt + 1);

#pragma unroll
    for (int s = 0; s < 2; ++s) {
      const int cs = s ? c1 : c0;
      bf16x8 a[4], b[4];
#pragma unroll
      for (int i = 0; i < 4; ++i) a[i] = *(const bf16x8*)(As + arow + i * 1024 + cs);
#pragma unroll
      for (int j = 0; j < 4; ++j) b[j] = *(const bf16x8*)(Bs + brow + j * 1024 + cs);
#pragma unroll
      for (int i = 0; i < 4; ++i)
#pragma unroll
        for (int j = 0; j < 4; ++j)
          acc[i][j] = __builtin_amdgcn_mfma_f32_16x16x32_bf16(a[i], b[j], acc[i][j], 0, 0, 0);
    }
  }

  const float* bAi = cq ? bgi : bfi;
  const float* bAh = cq ? bgh : bfh;
  const float* bBi = cq ? boi : bii;
  const float* bBh = cq ? boh : bih;
  float biasv[4];
  biasv[0] = bAi[hb + l15]      + bAh[hb + l15];
  biasv[1] = bAi[hb + 16 + l15] + bAh[hb + 16 + l15];
  biasv[2] = bBi[hb + l15]      + bBh[hb + l15];
  biasv[3] = bBi[hb + 16 + l15] + bBh[hb + 16 + l15];

  const size_t outCT = (size_t)8192 * 1024;

#pragma unroll
  for (int p = 0; p < 2; ++p) {
    __syncthreads();
    if (rq == p) {
#pragma unroll
      for (int j = 0; j < 4; ++j) {
        const int  n  = cq * 64 + j * 16 + l15;
        const bool ut = (cq == 1) && (j < 2);
        const float bj = biasv[j];
#pragma unroll
        for (int i = 0; i < 4; ++i)
#pragma unroll
          for (int r = 0; r < 4; ++r) {
            const float v = acc[i][j][r] + bj;
            Epi[(i * 16 + quad * 4 + r) * 132 + n] = ut ? ftanh(v) : fsigmoid(v);
          }
      }
    }
    __syncthreads();
#pragma unroll
    for (int it = 0; it < 8; ++it) {
      const int pair = it * 256 + tid;
      const int row  = pair >> 5;
      const int hl   = pair & 31;
      const float fv = Epi[row * 132 + hl];
      const float iv = Epi[row * 132 + 32 + hl];
      const float gv = Epi[row * 132 + 64 + hl];
      const float ov = Epi[row * 132 + 96 + hl];
      const size_t idx = (size_t)(bg0 + p * 64 + row) * 1024 + hb + hl;
      const float ctv = fv * c[idx] + iv * gv;
      const float htv = ov * ftanh(ctv);
      out[idx]         = htv;
      out[outCT + idx] = ctv;
    }
  }
}

extern "C" void kernel_launch(void* const* d_in, const int* in_sizes, int n_in,
                              void* d_out, int out_size, void* d_ws, size_t ws_size,
                              hipStream_t stream) {
  const float* p[19];
  for (int i = 0; i < 19; ++i) p[i] = (const float*)d_in[i];
  const size_t need = (size_t)24 * 1024 * 1024 * sizeof(bf16);   // 48 MB
  if (ws_size >= need) {
    prep_bf16<<<dim3(2048), dim3(256), 0, stream>>>(
        p[0], p[1],
        p[3], p[7], p[11], p[15],     // wfi wii wgi woi
        p[5], p[9], p[13], p[17],     // wfh wih wgh woh
        (bf16*)d_ws);
    lstm_mfma<<<dim3(512), dim3(512), 0, stream>>>(
        (const bf16*)d_ws, p[2],
        p[4], p[6], p[8], p[10], p[12], p[14], p[16], p[18],
        (float*)d_out);
  } else {
    lstm_fused<<<dim3(32, 64), dim3(256), 0, stream>>>(
        p[0], p[1], p[2],
        p[3], p[4], p[5], p[6],
        p[7], p[8], p[9], p[10],
        p[11], p[12], p[13], p[14],
        p[15], p[16], p[17], p[18],
        (float*)d_out);
  }
}